// Round 3
// baseline (140.497 us; speedup 1.0000x reference)
//
#include <hip/hip_runtime.h>
#include <math.h>

#define N_ROWS 524288
#define H_COLS 256
#define G_SEGS 8192
#define ROWS_PER_WAVE 64
#define WAVES_PER_BLOCK 4

// Perfectly balanced single pass: wave w owns rows [64w, 64w+64), streaming
// contiguous memory. ids are sorted, so a chunk spans ~2-3 segments; partials
// are flushed to the global accumulator (d_out itself) with atomicAdd on a
// wave-uniform segment-id change. Shift-free: exp(v) with |v|<=~6 is safely
// in fp32 range, and LSE is shift-invariant.
__global__ __launch_bounds__(256) void accum_exp(const float* __restrict__ x,
                                                 const int* __restrict__ ids,
                                                 float* __restrict__ acc) {
    const int wave = threadIdx.x >> 6;
    const int lane = threadIdx.x & 63;
    const int w = blockIdx.x * WAVES_PER_BLOCK + wave;
    const int r0 = w * ROWS_PER_WAVE;
    const int r1 = r0 + ROWS_PER_WAVE;

    const float4* __restrict__ xp = reinterpret_cast<const float4*>(x) + lane;

    int cur = ids[r0];
    float a0 = 0.f, a1 = 0.f, a2 = 0.f, a3 = 0.f;

#pragma unroll 4
    for (int r = r0; r < r1; ++r) {
        int id = ids[r];                       // wave-uniform, L1/L2-hit
        float4 v = xp[(size_t)r * (H_COLS / 4)];
        if (id != cur) {                       // wave-uniform, rare (~2.5/64)
            float* dst = acc + (size_t)cur * H_COLS + lane * 4;
            atomicAdd(dst + 0, a0);
            atomicAdd(dst + 1, a1);
            atomicAdd(dst + 2, a2);
            atomicAdd(dst + 3, a3);
            cur = id;
            a0 = a1 = a2 = a3 = 0.f;
        }
        a0 += __expf(v.x);
        a1 += __expf(v.y);
        a2 += __expf(v.z);
        a3 += __expf(v.w);
    }
    float* dst = acc + (size_t)cur * H_COLS + lane * 4;
    atomicAdd(dst + 0, a0);
    atomicAdd(dst + 1, a1);
    atomicAdd(dst + 2, a2);
    atomicAdd(dst + 3, a3);
}

// In-place log over the 8 MiB accumulator (= d_out).
__global__ __launch_bounds__(256) void finalize_log(float* __restrict__ buf) {
    int i = blockIdx.x * blockDim.x + threadIdx.x;
    float4 v = reinterpret_cast<float4*>(buf)[i];
    v.x = logf(v.x);
    v.y = logf(v.y);
    v.z = logf(v.z);
    v.w = logf(v.w);
    reinterpret_cast<float4*>(buf)[i] = v;
}

extern "C" void kernel_launch(void* const* d_in, const int* in_sizes, int n_in,
                              void* d_out, int out_size, void* d_ws, size_t ws_size,
                              hipStream_t stream) {
    const float* seq_rep = (const float*)d_in[0];
    const int* pair_ids = (const int*)d_in[1];
    float* out = (float*)d_out;  // doubles as the exp-sum accumulator

    // Zero the accumulator each call (harness poisons d_out, never re-zeros).
    hipMemsetAsync(out, 0, (size_t)G_SEGS * H_COLS * sizeof(float), stream);

    const int n_waves = N_ROWS / ROWS_PER_WAVE;                 // 8192
    accum_exp<<<n_waves / WAVES_PER_BLOCK, 256, 0, stream>>>(seq_rep, pair_ids, out);

    const int n_vec4 = G_SEGS * H_COLS / 4;                     // 524288
    finalize_log<<<n_vec4 / 256, 256, 0, stream>>>(out);
}

// Round 4
// 133.132 us; speedup vs baseline: 1.0553x; 1.0553x over previous
//
#include <hip/hip_runtime.h>
#include <math.h>

#define N_ROWS 524288
#define H_COLS 256
#define G_SEGS 8192
#define SEGS_PER_BLOCK 4

// Kernel 1: find segment start offsets from sorted pair_ids.
__global__ __launch_bounds__(256) void find_starts(const int* __restrict__ ids,
                                                   int* __restrict__ starts, int n) {
    int i = blockIdx.x * blockDim.x + threadIdx.x;
    if (i >= n) return;
    int id = ids[i];
    if (i == 0) {
        starts[id] = 0;
        starts[G_SEGS] = n;
    } else if (ids[i - 1] != id) {
        starts[id] = i;
    }
}

// Kernel 2: one wave per segment, lane l owns columns [4l,4l+3] via float4.
// Shift fixed from the segment's first row (LSE shift-invariance) so the loop
// body is sub+exp+add with only the add loop-carried. unroll 8 keeps 8
// independent 16B loads in flight per lane (latency-limited regime);
// __launch_bounds__(256,8) caps VGPR at 64 so all 8192 waves stay resident.
__global__ __launch_bounds__(256, 8) void seg_lse(const float* __restrict__ x,
                                                  const int* __restrict__ starts,
                                                  float* __restrict__ out) {
    const int wave = threadIdx.x >> 6;
    const int lane = threadIdx.x & 63;
    const int g = blockIdx.x * SEGS_PER_BLOCK + wave;

    const int s0 = starts[g];
    const int s1 = starts[g + 1];

    const float4* __restrict__ xp = reinterpret_cast<const float4*>(x) + lane;

    // Peel row s0: defines the shift; its own contribution is exp(0)=1.
    float4 mv = xp[(size_t)s0 * (H_COLS / 4)];
    const float m0 = mv.x, m1 = mv.y, m2 = mv.z, m3 = mv.w;
    float a0 = 1.f, a1 = 1.f, a2 = 1.f, a3 = 1.f;

#pragma unroll 8
    for (int r = s0 + 1; r < s1; ++r) {
        float4 v = xp[(size_t)r * (H_COLS / 4)];
        a0 += __expf(v.x - m0);
        a1 += __expf(v.y - m1);
        a2 += __expf(v.z - m2);
        a3 += __expf(v.w - m3);
    }

    float4 o;
    o.x = m0 + logf(a0);
    o.y = m1 + logf(a1);
    o.z = m2 + logf(a2);
    o.w = m3 + logf(a3);
    reinterpret_cast<float4*>(out)[(size_t)g * (H_COLS / 4) + lane] = o;
}

extern "C" void kernel_launch(void* const* d_in, const int* in_sizes, int n_in,
                              void* d_out, int out_size, void* d_ws, size_t ws_size,
                              hipStream_t stream) {
    const float* seq_rep = (const float*)d_in[0];
    const int* pair_ids = (const int*)d_in[1];
    float* out = (float*)d_out;
    int* starts = (int*)d_ws;  // G_SEGS + 1 ints

    int n = in_sizes[1];  // N_ROWS

    find_starts<<<(n + 255) / 256, 256, 0, stream>>>(pair_ids, starts, n);
    seg_lse<<<G_SEGS / SEGS_PER_BLOCK, 256, 0, stream>>>(seq_rep, starts, out);
}